// Round 4
// baseline (6452.394 us; speedup 1.0000x reference)
//
#include <hip/hip_runtime.h>

// RNN scan: h_{t+1} = 0.8*h_t + 0.2*(relu(h_t @ W_rec^T + b_rec + inp_t) + rn_t)
//
// R7 PAIR-BLOCK DESIGN. Facts from R0-R6:
//   - compiler budgets VGPRs for 2 workgroups/CU no matter what:
//     512t -> 128 regs, 1024t -> 64 regs (attrs/launch_bounds all ignored).
//   - VALUBusy*dur == clean issue floor every round -> all excess time is
//     spill-reload + W-stream stall (L2-resident, FETCH-invisible).
//   - 128 blocks on 256 CUs = half the machine idle.
// FIX: 256 blocks = 2 per chain. Block (b,half) owns rows [256h,256h+256).
// Per-thread W: 32 groups -> 16 NAMED regs (64 VGPRs, FITS the 128 budget)
// + 16 LDS groups (131KB). ZERO spill, ZERO stream. Issue/thread halves.
// h exchange: out[b][t+1] IS h_{t+1} -> out doubles as the exchange buffer.
//   writer: agent-scope atomic stores (cross-XCD coherent) -> __syncthreads
//   (drains vmcnt, measured compiler behavior) -> thread0 release-stores
//   flags[block]=t+1. reader ("late" waves = sibling-col half): spin relaxed
//   (sc-bypassed loads, never stale), one acquire, then agent loads of
//   out[b][t]. Early waves (own cols, h from LDS) run under the latency.
// All 256 blocks co-resident: 132KB LDS -> exactly 1 block/CU, grid = #CU.
// Spin has a bailout (no hang). t=0 peeled (h_0 = 0: no dots, no wait).
// PREDICT: dur -> 350-450us, VALUBusy 55-70%, FETCH ~+130MB, no spills.

#define B_  128
#define T_  512
#define N_  512
#define IN_ 6
#define TPB 512
#define NRG 16                      // W groups in VGPRs (64 regs)
#define NLG 16                      // W groups in LDS   (131072 B)

typedef _Float16 half2_t __attribute__((ext_vector_type(2)));

#if __has_builtin(__builtin_amdgcn_fdot2)
#define HAVE_FDOT2 1
#else
#define HAVE_FDOT2 0
#endif

__device__ __forceinline__ float dot2_acc(half2_t a, half2_t b, float c) {
#if HAVE_FDOT2
    return __builtin_amdgcn_fdot2(a, b, c, false);
#else
    c = fmaf((float)a[0], (float)b[0], c);
    c = fmaf((float)a[1], (float)b[1], c);
    return c;
#endif
}

__device__ __forceinline__ half2_t h2bits(unsigned s) {
    union { unsigned u; half2_t h; } cv; cv.u = s; return cv.h;
}

// 8 consecutive fp32 -> 8 packed fp16 in a uint4
__device__ __forceinline__ uint4 pack8(const float* __restrict__ p) {
    const float4 f0 = ((const float4*)p)[0];
    const float4 f1 = ((const float4*)p)[1];
    union { unsigned u[4]; half2_t h[4]; } cv;
    cv.h[0] = half2_t{(_Float16)f0.x, (_Float16)f0.y};
    cv.h[1] = half2_t{(_Float16)f0.z, (_Float16)f0.w};
    cv.h[2] = half2_t{(_Float16)f1.x, (_Float16)f1.y};
    cv.h[3] = half2_t{(_Float16)f1.z, (_Float16)f1.w};
    return uint4{cv.u[0], cv.u[1], cv.u[2], cv.u[3]};
}

// opaque redefinition: blocks rematerialization of the producing load
#define KEEP4(v) asm volatile("" : "+v"((v).x), "+v"((v).y), "+v"((v).z), "+v"((v).w))

// one 8-col group: 4 readlane-broadcast h pairs dotted into 4 accumulators.
// G is wave-uniform (v_readlane takes an SGPR index).
#define DOTG(W, G) do {                                                                    \
    a0 = dot2_acc(h2bits((W).x), h2bits((unsigned)__builtin_amdgcn_readlane(hx,(G))), a0); \
    a1 = dot2_acc(h2bits((W).y), h2bits((unsigned)__builtin_amdgcn_readlane(hy,(G))), a1); \
    a2 = dot2_acc(h2bits((W).z), h2bits((unsigned)__builtin_amdgcn_readlane(hz,(G))), a2); \
    a3 = dot2_acc(h2bits((W).w), h2bits((unsigned)__builtin_amdgcn_readlane(hw,(G))), a3); \
} while (0)

__device__ int fb_flags[B_ * 2];   // fallback flag storage if d_ws too small

__global__ __launch_bounds__(TPB)
void rnn_pair_kernel(
    const float* __restrict__ u,     // [B,T,IN]
    const float* __restrict__ unz,   // [B,T,IN]
    const float* __restrict__ rnz,   // [B,T,N]
    const float* __restrict__ Wrec,  // [N,N]
    const float* __restrict__ brec,  // [N]
    const float* __restrict__ Win,   // [N,IN]
    int*  flags,                     // [256], zeroed before launch
    float* out)                      // [B,T,N]  (also the h exchange medium)
{
    const int g    = blockIdx.x;     // 0..255
    const int b    = g >> 1;
    const int half = g & 1;          // owns rows [256*half, 256*half+256)
    const int tid  = threadIdx.x;
    const int r    = tid & 255;      // local row
    const bool early = (tid < 256);  // early: own-col half; late: sibling cols
    const int lane = tid & 63;
    const int grow = 256 * half + r;                     // global row
    const int colbase = early ? 256 * half : 256 * (1 - half);
    const int G0 = colbase >> 3;                         // wave-uniform

    __shared__ uint4 ltail[NLG][TPB];                // 131072 B
    __shared__ float pbuf[256];                      // 1024 B
    __shared__ __align__(16) _Float16 hown[256];     // 512 B

    const float* wrow = Wrec + (size_t)grow * N_ + colbase;

    // ---- one-time: groups 0..15 as 16 NAMED uint4 (64 VGPRs) ----
    uint4 w0  = pack8(wrow +   0); uint4 w1  = pack8(wrow +   8); uint4 w2  = pack8(wrow +  16); uint4 w3  = pack8(wrow +  24);
    uint4 w4  = pack8(wrow +  32); uint4 w5  = pack8(wrow +  40); uint4 w6  = pack8(wrow +  48); uint4 w7  = pack8(wrow +  56);
    uint4 w8  = pack8(wrow +  64); uint4 w9  = pack8(wrow +  72); uint4 w10 = pack8(wrow +  80); uint4 w11 = pack8(wrow +  88);
    uint4 w12 = pack8(wrow +  96); uint4 w13 = pack8(wrow + 104); uint4 w14 = pack8(wrow + 112); uint4 w15 = pack8(wrow + 120);

    KEEP4(w0);  KEEP4(w1);  KEEP4(w2);  KEEP4(w3);
    KEEP4(w4);  KEEP4(w5);  KEEP4(w6);  KEEP4(w7);
    KEEP4(w8);  KEEP4(w9);  KEEP4(w10); KEEP4(w11);
    KEEP4(w12); KEEP4(w13); KEEP4(w14); KEEP4(w15);

    // ---- one-time: groups 16..31 into LDS ----
#pragma unroll
    for (int j = 0; j < NLG; ++j)
        ltail[j][tid] = pack8(wrow + 8 * (NRG + j));

    // early-only persistent state
    float win0 = 0, win1 = 0, win2 = 0, win3 = 0, win4 = 0, win5 = 0, br = 0;
    float inp_c = 0, rn_c = 0, h = 0.0f;
    float* ob = out + (size_t)b * T_ * N_;
    const float* rb = rnz + (size_t)b * T_ * N_;
    const float2* ubp = (const float2*)(u   + (size_t)b * T_ * IN_);
    const float2* nbp = (const float2*)(unz + (size_t)b * T_ * IN_);
    const float NS = 0.6324555320336759f;  // sqrt(2/alpha * sigma^2)

    if (early) {
        win0 = Win[grow * IN_ + 0]; win1 = Win[grow * IN_ + 1]; win2 = Win[grow * IN_ + 2];
        win3 = Win[grow * IN_ + 3]; win4 = Win[grow * IN_ + 4]; win5 = Win[grow * IN_ + 5];
        br = brec[grow];
        float2 cu0 = ubp[0], cu1 = ubp[1], cu2 = ubp[2];
        float2 cn0 = nbp[0], cn1 = nbp[1], cn2 = nbp[2];
        inp_c = br;
        inp_c = fmaf(win0, fmaf(NS, cn0.x, cu0.x), inp_c);
        inp_c = fmaf(win1, fmaf(NS, cn0.y, cu0.y), inp_c);
        inp_c = fmaf(win2, fmaf(NS, cn1.x, cu1.x), inp_c);
        inp_c = fmaf(win3, fmaf(NS, cn1.y, cu1.y), inp_c);
        inp_c = fmaf(win4, fmaf(NS, cn2.x, cu2.x), inp_c);
        inp_c = fmaf(win5, fmaf(NS, cn2.y, cu2.y), inp_c);
        rn_c = rb[grow];
    }

    // ---- peel t = 0: h_0 = 0, so pre = inp only; no dots, no exchange ----
    if (early) {
        ob[grow] = 0.0f;                              // states[0]
        h = 0.2f * (fmaxf(inp_c, 0.0f) + rn_c);       // h_1
        hown[r] = (_Float16)h;
        __hip_atomic_store(ob + N_ + grow, h, __ATOMIC_RELAXED, __HIP_MEMORY_SCOPE_AGENT);
        // prefetch step-1 inputs
        float2 pu0 = ubp[3], pu1 = ubp[4], pu2 = ubp[5];
        float2 pn0 = nbp[3], pn1 = nbp[4], pn2 = nbp[5];
        float inp_n = br;
        inp_n = fmaf(win0, fmaf(NS, pn0.x, pu0.x), inp_n);
        inp_n = fmaf(win1, fmaf(NS, pn0.y, pu0.y), inp_n);
        inp_n = fmaf(win2, fmaf(NS, pn1.x, pu1.x), inp_n);
        inp_n = fmaf(win3, fmaf(NS, pn1.y, pu1.y), inp_n);
        inp_n = fmaf(win4, fmaf(NS, pn2.x, pu2.x), inp_n);
        inp_n = fmaf(win5, fmaf(NS, pn2.y, pu2.y), inp_n);
        inp_c = inp_n;
        rn_c  = rb[N_ + grow];
    }
    __syncthreads();   // drains all stores (compiler emits vmcnt(0) before barrier)
    if (tid == 0) __hip_atomic_store(&flags[g], 1, __ATOMIC_RELEASE, __HIP_MEMORY_SCOPE_AGENT);

#pragma unroll 1
    for (int t = 1; t < T_ - 1; ++t) {
        // ---- obtain h_t groups: lane l holds h[8l..8l+8] (its quadrant) ----
        uint4 hv;
        if (early) {
            hv = ((const uint4*)hown)[lane & 31];     // own half from LDS
        } else {
            const int sib = g ^ 1;
            int it = 0;
            while (__hip_atomic_load(&flags[sib], __ATOMIC_RELAXED, __HIP_MEMORY_SCOPE_AGENT) < t) {
                __builtin_amdgcn_s_sleep(1);
                if (++it > 1000000) break;            // bailout: never hang
            }
            (void)__hip_atomic_load(&flags[sib], __ATOMIC_ACQUIRE, __HIP_MEMORY_SCOPE_AGENT);
            float* src = out + ((size_t)b * T_ + t) * N_ + 8 * (G0 + (lane & 31));
            float f0 = __hip_atomic_load(src + 0, __ATOMIC_RELAXED, __HIP_MEMORY_SCOPE_AGENT);
            float f1 = __hip_atomic_load(src + 1, __ATOMIC_RELAXED, __HIP_MEMORY_SCOPE_AGENT);
            float f2 = __hip_atomic_load(src + 2, __ATOMIC_RELAXED, __HIP_MEMORY_SCOPE_AGENT);
            float f3 = __hip_atomic_load(src + 3, __ATOMIC_RELAXED, __HIP_MEMORY_SCOPE_AGENT);
            float f4 = __hip_atomic_load(src + 4, __ATOMIC_RELAXED, __HIP_MEMORY_SCOPE_AGENT);
            float f5 = __hip_atomic_load(src + 5, __ATOMIC_RELAXED, __HIP_MEMORY_SCOPE_AGENT);
            float f6 = __hip_atomic_load(src + 6, __ATOMIC_RELAXED, __HIP_MEMORY_SCOPE_AGENT);
            float f7 = __hip_atomic_load(src + 7, __ATOMIC_RELAXED, __HIP_MEMORY_SCOPE_AGENT);
            union { unsigned uu[4]; half2_t hh[4]; } cv;
            cv.hh[0] = half2_t{(_Float16)f0, (_Float16)f1};
            cv.hh[1] = half2_t{(_Float16)f2, (_Float16)f3};
            cv.hh[2] = half2_t{(_Float16)f4, (_Float16)f5};
            cv.hh[3] = half2_t{(_Float16)f6, (_Float16)f7};
            hv = uint4{cv.uu[0], cv.uu[1], cv.uu[2], cv.uu[3]};
        }
        const int hx = (int)hv.x, hy = (int)hv.y, hz = (int)hv.z, hw = (int)hv.w;

        // prefetch step t+1 inputs (early only; consumed after the dots)
        float rn_n = 0.0f;
        float2 pu0{0,0}, pu1{0,0}, pu2{0,0}, pn0{0,0}, pn1{0,0}, pn2{0,0};
        if (early) {
            rn_n = rb[(size_t)(t + 1) * N_ + grow];
            pu0 = ubp[(t + 1) * 3 + 0]; pu1 = ubp[(t + 1) * 3 + 1]; pu2 = ubp[(t + 1) * 3 + 2];
            pn0 = nbp[(t + 1) * 3 + 0]; pn1 = nbp[(t + 1) * 3 + 1]; pn2 = nbp[(t + 1) * 3 + 2];
        }

        float a0 = early ? inp_c : 0.0f, a1 = 0.0f, a2 = 0.0f, a3 = 0.0f;

        // LDS batch A (groups 16..19)
        uint4 la0 = ltail[0][tid], la1 = ltail[1][tid], la2 = ltail[2][tid], la3 = ltail[3][tid];

        DOTG(w0, G0 + 0);  DOTG(w1, G0 + 1);  DOTG(w2, G0 + 2);  DOTG(w3, G0 + 3);
        DOTG(w4, G0 + 4);  DOTG(w5, G0 + 5);  DOTG(w6, G0 + 6);  DOTG(w7, G0 + 7);

        // LDS batch B (groups 20..23)
        uint4 lb0 = ltail[4][tid], lb1 = ltail[5][tid], lb2 = ltail[6][tid], lb3 = ltail[7][tid];

        DOTG(w8, G0 + 8);   DOTG(w9, G0 + 9);   DOTG(w10, G0 + 10); DOTG(w11, G0 + 11);
        DOTG(w12, G0 + 12); DOTG(w13, G0 + 13); DOTG(w14, G0 + 14); DOTG(w15, G0 + 15);

        // LDS batch C (groups 24..27)
        uint4 lc0 = ltail[8][tid], lc1 = ltail[9][tid], lc2 = ltail[10][tid], lc3 = ltail[11][tid];

        DOTG(la0, G0 + 16); DOTG(la1, G0 + 17); DOTG(la2, G0 + 18); DOTG(la3, G0 + 19);

        // LDS batch D (groups 28..31)
        uint4 ld0 = ltail[12][tid], ld1 = ltail[13][tid], ld2 = ltail[14][tid], ld3 = ltail[15][tid];

        DOTG(lb0, G0 + 20); DOTG(lb1, G0 + 21); DOTG(lb2, G0 + 22); DOTG(lb3, G0 + 23);
        DOTG(lc0, G0 + 24); DOTG(lc1, G0 + 25); DOTG(lc2, G0 + 26); DOTG(lc3, G0 + 27);
        DOTG(ld0, G0 + 28); DOTG(ld1, G0 + 29); DOTG(ld2, G0 + 30); DOTG(ld3, G0 + 31);

        const float partial = (a0 + a1) + (a2 + a3);
        if (!early) pbuf[r] = partial;
        __syncthreads();

        if (early) {
            const float pre = partial + pbuf[r];
            h = 0.8f * h + 0.2f * (fmaxf(pre, 0.0f) + rn_c);
            hown[r] = (_Float16)h;
            __hip_atomic_store(ob + (size_t)(t + 1) * N_ + grow, h,
                               __ATOMIC_RELAXED, __HIP_MEMORY_SCOPE_AGENT);
            float inp_n = br;
            inp_n = fmaf(win0, fmaf(NS, pn0.x, pu0.x), inp_n);
            inp_n = fmaf(win1, fmaf(NS, pn0.y, pu0.y), inp_n);
            inp_n = fmaf(win2, fmaf(NS, pn1.x, pu1.x), inp_n);
            inp_n = fmaf(win3, fmaf(NS, pn1.y, pu1.y), inp_n);
            inp_n = fmaf(win4, fmaf(NS, pn2.x, pu2.x), inp_n);
            inp_n = fmaf(win5, fmaf(NS, pn2.y, pu2.y), inp_n);
            inp_c = inp_n;
            rn_c  = rn_n;
        }
        __syncthreads();   // drains the agent stores in every wave
        if (tid == 0) __hip_atomic_store(&flags[g], t + 1,
                                         __ATOMIC_RELEASE, __HIP_MEMORY_SCOPE_AGENT);
    }
}

extern "C" void kernel_launch(void* const* d_in, const int* in_sizes, int n_in,
                              void* d_out, int out_size, void* d_ws, size_t ws_size,
                              hipStream_t stream) {
    const float* u    = (const float*)d_in[0];
    const float* unz  = (const float*)d_in[1];
    const float* rnz  = (const float*)d_in[2];
    const float* Wrec = (const float*)d_in[3];
    const float* brec = (const float*)d_in[4];
    const float* Win  = (const float*)d_in[5];
    float* out = (float*)d_out;

    int* flags = nullptr;
    if (ws_size >= (size_t)(B_ * 2) * sizeof(int)) {
        flags = (int*)d_ws;
    } else {
        hipGetSymbolAddress((void**)&flags, HIP_SYMBOL(fb_flags));
    }
    hipMemsetAsync(flags, 0, (size_t)(B_ * 2) * sizeof(int), stream);
    rnn_pair_kernel<<<dim3(B_ * 2), dim3(TPB), 0, stream>>>(
        u, unz, rnz, Wrec, brec, Win, flags, out);
}

// Round 5
// 1319.928 us; speedup vs baseline: 4.8884x; 4.8884x over previous
//
#include <hip/hip_runtime.h>

// RNN scan: h_{t+1} = 0.8*h_t + 0.2*(relu(h_t @ W_rec^T + b_rec + inp_t) + rn_t)
// 128 chains -> 128 blocks x 512 threads, thread n owns row n of W_rec (fp16).
//
// R8 ZERO-SPILL DESIGN. Facts established R0-R7:
//   - 512t kernels get a hard 128-VGPR cap (attrs/launch_bounds ignored);
//     1024t -> 64.  R4 measured: 16 named W groups + batched LDS -> VGPR=100,
//     i.e. a design whose TRUE need fits the cap gets it, zero spills.
//   - R2 (best, 1331us) had true need ~240 vs 128 -> ~110 regs allocator-
//     spilled to scratch, reloaded serially every step = the 60% stall.
//   - cross-block per-step sync costs ~10us/step (R7): single block per chain.
// FIX: manual spill = software-pipelined L2 stream. W row = 64 groups:
//   groups  0..15 -> 16 NAMED uint4 SSA values (64 VGPRs)
//   groups 16..34 -> LDS ltail[19][512] uint4 (155648 B; +hbuf = 157696,
//                    under the 160 KiB LDS max)
//   groups 35..63 -> fp16 image in d_ws, streamed from L2 in batches of 4,
//                    issued 2 batches ahead (464 B/thr/step, ~3.2 TB/s/XCD)
// True reg need ~125 <= 128 cap -> zero allocator spills.
// PREDICT: VGPR ~110-128, VALUBusy 65-80%, dur 600-750us, LDS ~157696.
//
// h broadcast: one ds_read_b128 per lane (lane l holds h[8l..8l+8]), then
// v_readlane with constant lane index feeds v_dot2_f32_f16's SGPR operand.

#define B_  128
#define T_  512
#define N_  512
#define IN_ 6

#define NREGG  16                    // groups in VGPRs   (cols 0..128)
#define NLDSG  19                    // groups in LDS     (cols 128..280)
#define NWSG   29                    // groups from d_ws  (cols 280..512)
#define LDS_C0 (8 * NREGG)           // 128
#define WS_C0  (8 * (NREGG + NLDSG)) // 280
#define GL     (NREGG)               // first LDS group index (16)
#define GS     (NREGG + NLDSG)       // first ws  group index (35)

typedef _Float16 half2_t __attribute__((ext_vector_type(2)));

#if __has_builtin(__builtin_amdgcn_fdot2)
#define HAVE_FDOT2 1
#else
#define HAVE_FDOT2 0
#endif

__device__ __forceinline__ float dot2_acc(half2_t a, half2_t b, float c) {
#if HAVE_FDOT2
    return __builtin_amdgcn_fdot2(a, b, c, false);
#else
    c = fmaf((float)a[0], (float)b[0], c);
    c = fmaf((float)a[1], (float)b[1], c);
    return c;
#endif
}

__device__ __forceinline__ half2_t h2bits(unsigned s) {
    union { unsigned u; half2_t h; } cv; cv.u = s; return cv.h;
}

// 8 consecutive fp32 -> 8 packed fp16 in a uint4
__device__ __forceinline__ uint4 pack8(const float* __restrict__ p) {
    const float4 f0 = ((const float4*)p)[0];
    const float4 f1 = ((const float4*)p)[1];
    union { unsigned u[4]; half2_t h[4]; } cv;
    cv.h[0] = half2_t{(_Float16)f0.x, (_Float16)f0.y};
    cv.h[1] = half2_t{(_Float16)f0.z, (_Float16)f0.w};
    cv.h[2] = half2_t{(_Float16)f1.x, (_Float16)f1.y};
    cv.h[3] = half2_t{(_Float16)f1.z, (_Float16)f1.w};
    return uint4{cv.u[0], cv.u[1], cv.u[2], cv.u[3]};
}

// opaque redefinition: blocks rematerialization of the producing load
#define KEEP4(v) asm volatile("" : "+v"((v).x), "+v"((v).y), "+v"((v).z), "+v"((v).w))

// ---- prep: W_rec cols [WS_C0,512) -> fp16 image, layout [NWSG][N_] uint4 ----
__global__ void prep_tail_kernel(const float* __restrict__ Wrec,
                                 uint4* __restrict__ ws) {
    int tid = blockIdx.x * blockDim.x + threadIdx.x;
    if (tid >= NWSG * N_) return;
    int g = tid >> 9, n = tid & (N_ - 1);
    ws[(size_t)g * N_ + n] = pack8(Wrec + (size_t)n * N_ + WS_C0 + 8 * g);
}

template <bool USE_WS>
__device__ __forceinline__ uint4 gload(const uint4* __restrict__ wsn,
                                       const float* __restrict__ wrow_ws, int k) {
    if constexpr (USE_WS) return wsn[k * N_];
    else return pack8(wrow_ws + 8 * k);
}

// one 8-col group: 4 readlane-broadcast h pairs dotted into 4 accumulators
#define DOTG(W, G) do {                                                                    \
    a0 = dot2_acc(h2bits((W).x), h2bits((unsigned)__builtin_amdgcn_readlane(hx,(G))), a0); \
    a1 = dot2_acc(h2bits((W).y), h2bits((unsigned)__builtin_amdgcn_readlane(hy,(G))), a1); \
    a2 = dot2_acc(h2bits((W).z), h2bits((unsigned)__builtin_amdgcn_readlane(hz,(G))), a2); \
    a3 = dot2_acc(h2bits((W).w), h2bits((unsigned)__builtin_amdgcn_readlane(hw,(G))), a3); \
} while (0)

template <bool USE_WS>
__global__ __launch_bounds__(512)
void rnn_scan_kernel(
    const float* __restrict__ u,     // [B,T,IN]
    const float* __restrict__ unz,   // [B,T,IN]
    const float* __restrict__ rnz,   // [B,T,N]
    const float* __restrict__ Wrec,  // [N,N]
    const float* __restrict__ brec,  // [N]
    const float* __restrict__ Win,   // [N,IN]
    const uint4* __restrict__ ws,    // fp16 tail image [NWSG][N_]
    float* __restrict__ out)         // [B,T,N]
{
    const int b = blockIdx.x;
    const int n = threadIdx.x;
    const int lane = n & 63;

    __shared__ uint4 ltail[NLDSG][N_];               // 155648 B
    __shared__ __align__(16) _Float16 hbuf[2][N_];   // 2048 B -> total 157696

    const float* wrow = Wrec + (size_t)n * N_;

    // ---- one-time: groups 0..15 as 16 NAMED uint4 (64 VGPRs) ----
    uint4 w0  = pack8(wrow +   0); uint4 w1  = pack8(wrow +   8); uint4 w2  = pack8(wrow +  16); uint4 w3  = pack8(wrow +  24);
    uint4 w4  = pack8(wrow +  32); uint4 w5  = pack8(wrow +  40); uint4 w6  = pack8(wrow +  48); uint4 w7  = pack8(wrow +  56);
    uint4 w8  = pack8(wrow +  64); uint4 w9  = pack8(wrow +  72); uint4 w10 = pack8(wrow +  80); uint4 w11 = pack8(wrow +  88);
    uint4 w12 = pack8(wrow +  96); uint4 w13 = pack8(wrow + 104); uint4 w14 = pack8(wrow + 112); uint4 w15 = pack8(wrow + 120);

    KEEP4(w0);  KEEP4(w1);  KEEP4(w2);  KEEP4(w3);
    KEEP4(w4);  KEEP4(w5);  KEEP4(w6);  KEEP4(w7);
    KEEP4(w8);  KEEP4(w9);  KEEP4(w10); KEEP4(w11);
    KEEP4(w12); KEEP4(w13); KEEP4(w14); KEEP4(w15);

    // ---- one-time: groups 16..34 into LDS ----
#pragma unroll
    for (int j = 0; j < NLDSG; ++j)
        ltail[j][n] = pack8(wrow + LDS_C0 + 8 * j);

    const float win0 = Win[n * IN_ + 0], win1 = Win[n * IN_ + 1], win2 = Win[n * IN_ + 2];
    const float win3 = Win[n * IN_ + 3], win4 = Win[n * IN_ + 4], win5 = Win[n * IN_ + 5];
    const float br = brec[n];
    const uint4* wsn = ws + n;
    const float* wrow_ws = wrow + WS_C0;

    const float NS = 0.6324555320336759f;  // sqrt(2/alpha * sigma^2)
    float h = 0.0f;

    float* ob = out + (size_t)b * T_ * N_;
    const float* rb = rnz + (size_t)b * T_ * N_;
    const float2* ubp = (const float2*)(u   + (size_t)b * T_ * IN_);
    const float2* nbp = (const float2*)(unz + (size_t)b * T_ * IN_);

    hbuf[0][n] = (_Float16)0.0f;

    // inp for t=0
    float2 cu0 = ubp[0], cu1 = ubp[1], cu2 = ubp[2];
    float2 cn0 = nbp[0], cn1 = nbp[1], cn2 = nbp[2];
    float inp_c = br;
    inp_c = fmaf(win0, fmaf(NS, cn0.x, cu0.x), inp_c);
    inp_c = fmaf(win1, fmaf(NS, cn0.y, cu0.y), inp_c);
    inp_c = fmaf(win2, fmaf(NS, cn1.x, cu1.x), inp_c);
    inp_c = fmaf(win3, fmaf(NS, cn1.y, cu1.y), inp_c);
    inp_c = fmaf(win4, fmaf(NS, cn2.x, cu2.x), inp_c);
    inp_c = fmaf(win5, fmaf(NS, cn2.y, cu2.y), inp_c);
    float rn_c = rb[n];
    __syncthreads();

#pragma unroll 1
    for (int t = 0; t < T_ - 1; ++t) {
        ob[(size_t)t * N_ + n] = h;   // states[t] (t=0: zeros)

        // this wave's copy of full h: lane l -> h[8l..8l+8]
        const uint4 hv = ((const uint4*)hbuf[t & 1])[lane];
        const int hx = (int)hv.x, hy = (int)hv.y, hz = (int)hv.z, hw = (int)hv.w;

        // rn prefetch early (the one true HBM stream: needs ~900cy of lead)
        const float rn_n = rb[(size_t)(t + 1) * N_ + n];

        float a0 = inp_c, a1 = 0.0f, a2 = 0.0f, a3 = 0.0f;

        // ---- software pipeline: ws batches of 4, issued 2 batches ahead ----
        uint4 s0 = gload<USE_WS>(wsn, wrow_ws, 0), s1 = gload<USE_WS>(wsn, wrow_ws, 1),
              s2 = gload<USE_WS>(wsn, wrow_ws, 2), s3 = gload<USE_WS>(wsn, wrow_ws, 3);

        DOTG(w0, 0);  DOTG(w1, 1);  DOTG(w2, 2);  DOTG(w3, 3);

        uint4 s4 = gload<USE_WS>(wsn, wrow_ws, 4), s5 = gload<USE_WS>(wsn, wrow_ws, 5),
              s6 = gload<USE_WS>(wsn, wrow_ws, 6), s7 = gload<USE_WS>(wsn, wrow_ws, 7);

        DOTG(w4, 4);  DOTG(w5, 5);  DOTG(w6, 6);  DOTG(w7, 7);
        DOTG(w8, 8);  DOTG(w9, 9);  DOTG(w10, 10); DOTG(w11, 11);

        uint4 l0 = ltail[0][n], l1 = ltail[1][n], l2 = ltail[2][n], l3 = ltail[3][n];

        DOTG(w12, 12); DOTG(w13, 13); DOTG(w14, 14); DOTG(w15, 15);
        DOTG(s0, GS + 0); DOTG(s1, GS + 1); DOTG(s2, GS + 2); DOTG(s3, GS + 3);

        uint4 s8  = gload<USE_WS>(wsn, wrow_ws, 8),  s9  = gload<USE_WS>(wsn, wrow_ws, 9),
              s10 = gload<USE_WS>(wsn, wrow_ws, 10), s11 = gload<USE_WS>(wsn, wrow_ws, 11);
        uint4 l4 = ltail[4][n], l5 = ltail[5][n], l6 = ltail[6][n], l7 = ltail[7][n];

        DOTG(l0, GL + 0); DOTG(l1, GL + 1); DOTG(l2, GL + 2); DOTG(l3, GL + 3);
        DOTG(s4, GS + 4); DOTG(s5, GS + 5); DOTG(s6, GS + 6); DOTG(s7, GS + 7);

        uint4 s12 = gload<USE_WS>(wsn, wrow_ws, 12), s13 = gload<USE_WS>(wsn, wrow_ws, 13),
              s14 = gload<USE_WS>(wsn, wrow_ws, 14), s15 = gload<USE_WS>(wsn, wrow_ws, 15);
        uint4 l8 = ltail[8][n], l9 = ltail[9][n], l10 = ltail[10][n], l11 = ltail[11][n];

        DOTG(l4, GL + 4); DOTG(l5, GL + 5); DOTG(l6, GL + 6); DOTG(l7, GL + 7);
        DOTG(s8, GS + 8); DOTG(s9, GS + 9); DOTG(s10, GS + 10); DOTG(s11, GS + 11);

        uint4 s16 = gload<USE_WS>(wsn, wrow_ws, 16), s17 = gload<USE_WS>(wsn, wrow_ws, 17),
              s18 = gload<USE_WS>(wsn, wrow_ws, 18), s19 = gload<USE_WS>(wsn, wrow_ws, 19);
        uint4 l12 = ltail[12][n], l13 = ltail[13][n], l14 = ltail[14][n], l15 = ltail[15][n];

        DOTG(l8, GL + 8);  DOTG(l9, GL + 9);  DOTG(l10, GL + 10); DOTG(l11, GL + 11);
        DOTG(s12, GS + 12); DOTG(s13, GS + 13); DOTG(s14, GS + 14); DOTG(s15, GS + 15);

        // u/unz for t+1 (L1-resident after the first pass; loaded late to
        // keep liveness low while the ws stream is in flight)
        const float2 pu0 = ubp[(t + 1) * 3 + 0], pu1 = ubp[(t + 1) * 3 + 1], pu2 = ubp[(t + 1) * 3 + 2];
        const float2 pn0 = nbp[(t + 1) * 3 + 0], pn1 = nbp[(t + 1) * 3 + 1], pn2 = nbp[(t + 1) * 3 + 2];

        uint4 s20 = gload<USE_WS>(wsn, wrow_ws, 20), s21 = gload<USE_WS>(wsn, wrow_ws, 21),
              s22 = gload<USE_WS>(wsn, wrow_ws, 22), s23 = gload<USE_WS>(wsn, wrow_ws, 23);
        uint4 l16 = ltail[16][n], l17 = ltail[17][n], l18 = ltail[18][n];

        DOTG(l12, GL + 12); DOTG(l13, GL + 13); DOTG(l14, GL + 14); DOTG(l15, GL + 15);
        DOTG(s16, GS + 16); DOTG(s17, GS + 17); DOTG(s18, GS + 18); DOTG(s19, GS + 19);

        uint4 s24 = gload<USE_WS>(wsn, wrow_ws, 24), s25 = gload<USE_WS>(wsn, wrow_ws, 25),
              s26 = gload<USE_WS>(wsn, wrow_ws, 26), s27 = gload<USE_WS>(wsn, wrow_ws, 27),
              s28 = gload<USE_WS>(wsn, wrow_ws, 28);

        DOTG(l16, GL + 16); DOTG(l17, GL + 17); DOTG(l18, GL + 18);
        DOTG(s20, GS + 20); DOTG(s21, GS + 21); DOTG(s22, GS + 22); DOTG(s23, GS + 23);
        DOTG(s24, GS + 24); DOTG(s25, GS + 25); DOTG(s26, GS + 26); DOTG(s27, GS + 27);
        DOTG(s28, GS + 28);

        const float pre = (a0 + a1) + (a2 + a3);
        h = 0.8f * h + 0.2f * (fmaxf(pre, 0.0f) + rn_c);
        hbuf[(t + 1) & 1][n] = (_Float16)h;

        float inp_n = br;
        inp_n = fmaf(win0, fmaf(NS, pn0.x, pu0.x), inp_n);
        inp_n = fmaf(win1, fmaf(NS, pn0.y, pu0.y), inp_n);
        inp_n = fmaf(win2, fmaf(NS, pn1.x, pu1.x), inp_n);
        inp_n = fmaf(win3, fmaf(NS, pn1.y, pu1.y), inp_n);
        inp_n = fmaf(win4, fmaf(NS, pn2.x, pu2.x), inp_n);
        inp_n = fmaf(win5, fmaf(NS, pn2.y, pu2.y), inp_n);
        inp_c = inp_n;
        rn_c  = rn_n;
        __syncthreads();
    }
    ob[(size_t)(T_ - 1) * N_ + n] = h;  // states[511]
}

extern "C" void kernel_launch(void* const* d_in, const int* in_sizes, int n_in,
                              void* d_out, int out_size, void* d_ws, size_t ws_size,
                              hipStream_t stream) {
    const float* u    = (const float*)d_in[0];
    const float* unz  = (const float*)d_in[1];
    const float* rnz  = (const float*)d_in[2];
    const float* Wrec = (const float*)d_in[3];
    const float* brec = (const float*)d_in[4];
    const float* Win  = (const float*)d_in[5];
    float* out = (float*)d_out;

    const size_t ws_need = (size_t)NWSG * N_ * sizeof(uint4);  // 237568 B
    if (ws_size >= ws_need) {
        uint4* ws = (uint4*)d_ws;
        prep_tail_kernel<<<(NWSG * N_ + 255) / 256, 256, 0, stream>>>(Wrec, ws);
        rnn_scan_kernel<true><<<dim3(B_), dim3(N_), 0, stream>>>(
            u, unz, rnz, Wrec, brec, Win, ws, out);
    } else {
        rnn_scan_kernel<false><<<dim3(B_), dim3(N_), 0, stream>>>(
            u, unz, rnz, Wrec, brec, Win, nullptr, out);
    }
}

// Round 6
// 940.600 us; speedup vs baseline: 6.8599x; 1.4033x over previous
//
#include <hip/hip_runtime.h>

// RNN scan: h_{t+1} = 0.8*h_t + 0.2*(relu(h_t @ W_rec^T + b_rec + inp_t) + rn_t)
// 128 chains -> 128 blocks x 512 threads.
//
// R9 MFMA DESIGN. R0/R2/R5 invariant: VALUBusy*dur == VALU issue floor
// (~475us) + ~710us stall that no W-staging rebalance touches -> the
// readlane+dot2 engine itself is the ceiling. Replace it with the matrix
// pipe: per step per block, out(512) = W(512x512) h(512) via 512
// v_mfma_f32_16x16x32_f16 (64 per wave), B = h-slice replicated across all
// 16 columns (so every D column is the valid GEMV result).
//
// Fragment layouts (AMD matrix-core doc; D verified in-guide):
//   A: lane l holds W[rowbase + (l&15)][32kk + 8*(l>>4) + e]  (e=0..7)
//   B: lane l holds h[32kk + 8*(l>>4) + e], identical for all 16 cols
//   D: col = l&15 (all equal), row = rowbase + 4*(l>>4) + r  (r=0..3)
// Readout: lanes with (l&15)==0 ds_write their 4 rows to pre[], barrier,
// thread n does the h-update for row n (inp/rn pipeline unchanged from R5).
//
// W residency per wave (4 tiles x 16 kk = 64 A-frags):
//   kk 0..2  -> 12 NAMED uint4 (48 VGPRs)
//   kk 3..6  -> LDS lw[16][512] uint4 (131072 B)
//   kk 7..15 -> fp16 ws image, streamed (288 KB/block/step), 2-deep
//               double-banked pipeline (sa/sb, 32 VGPRs in flight)
// True reg need ~125 <= the 128 cap -> no allocator spills.
// PREDICT: MfmaUtil 0 -> 15-30, VALUBusy -> 10-20%, dur -> 550-750us.

#define B_  128
#define T_  512
#define N_  512
#define IN_ 6

typedef _Float16 f16x8 __attribute__((ext_vector_type(8)));
typedef float    f32x4 __attribute__((ext_vector_type(4)));
typedef _Float16 h2_t  __attribute__((ext_vector_type(2)));

union U4H8 { uint4 u; f16x8 h; };
__device__ __forceinline__ f16x8 h8(uint4 v) { U4H8 c; c.u = v; return c.h; }

// 8 consecutive fp32 -> 8 packed fp16 in a uint4
__device__ __forceinline__ uint4 pack8(const float* __restrict__ p) {
    const float4 f0 = ((const float4*)p)[0];
    const float4 f1 = ((const float4*)p)[1];
    union { unsigned u[4]; h2_t h[4]; } cv;
    cv.h[0] = h2_t{(_Float16)f0.x, (_Float16)f0.y};
    cv.h[1] = h2_t{(_Float16)f0.z, (_Float16)f0.w};
    cv.h[2] = h2_t{(_Float16)f1.x, (_Float16)f1.y};
    cv.h[3] = h2_t{(_Float16)f1.z, (_Float16)f1.w};
    return uint4{cv.u[0], cv.u[1], cv.u[2], cv.u[3]};
}

// opaque redefinition: blocks rematerialization of the producing load
#define KEEP4(v) asm volatile("" : "+v"((v).x), "+v"((v).y), "+v"((v).z), "+v"((v).w))

#define MFMA(A, Bv, C) __builtin_amdgcn_mfma_f32_16x16x32_f16(h8(A), h8(Bv), (C), 0, 0, 0)

// ---- prep: W_rec cols [224,512) -> fp16 image ws[g][n] = W[n][224+8g..+8] ----
__global__ void prep_tail_kernel(const float* __restrict__ Wrec,
                                 uint4* __restrict__ ws) {
    int tid = blockIdx.x * blockDim.x + threadIdx.x;
    if (tid >= 36 * N_) return;
    int g = tid >> 9, n = tid & (N_ - 1);
    ws[(size_t)g * N_ + n] = pack8(Wrec + (size_t)n * N_ + 224 + 8 * g);
}

// streamed A-frag (kk in 7..15): lane needs W[rowA+16T][32KK + 8q .. +8]
template <bool USE_WS>
__device__ __forceinline__ uint4 sld(const uint4* __restrict__ wsb,
                                     const float* __restrict__ Wrec,
                                     int rowA, int q, int KK, int T) {
    if constexpr (USE_WS) return wsb[2048 * (KK - 7) + 16 * T];
    else return pack8(Wrec + (size_t)(rowA + 16 * T) * N_ + 32 * KK + 8 * q);
}

template <bool USE_WS>
__global__ __launch_bounds__(512)
void rnn_scan_kernel(
    const float* __restrict__ u,     // [B,T,IN]
    const float* __restrict__ unz,   // [B,T,IN]
    const float* __restrict__ rnz,   // [B,T,N]
    const float* __restrict__ Wrec,  // [N,N]
    const float* __restrict__ brec,  // [N]
    const float* __restrict__ Win,   // [N,IN]
    const uint4* __restrict__ ws,    // fp16 tail image [36][N_]
    float* __restrict__ out)         // [B,T,N]
{
    const int b    = blockIdx.x;
    const int n    = threadIdx.x;
    const int w    = n >> 6;          // wave id: output rows 64w..64w+63
    const int lane = n & 63;
    const int q    = lane >> 4;       // k-subgroup
    const int r16  = lane & 15;       // A row-within-tile

    __shared__ uint4 lw[16 * N_];                    // 131072 B  (kk=3..6)
    __shared__ __align__(16) _Float16 hbuf[2][N_];   // 2048 B
    __shared__ float pre[N_];                        // 2048 B

    const int rowA = 64 * w + r16;
    const float* wp = Wrec + (size_t)rowA * N_ + 8 * q;  // + T*8192 + K*32

    // ---- one-time: A-frags kk=0..2 as 12 NAMED uint4 (48 VGPRs) ----
    uint4 a00 = pack8(wp +     0 +  0), a01 = pack8(wp +     0 + 32), a02 = pack8(wp +     0 + 64);
    uint4 a10 = pack8(wp +  8192 +  0), a11 = pack8(wp +  8192 + 32), a12 = pack8(wp +  8192 + 64);
    uint4 a20 = pack8(wp + 16384 +  0), a21 = pack8(wp + 16384 + 32), a22 = pack8(wp + 16384 + 64);
    uint4 a30 = pack8(wp + 24576 +  0), a31 = pack8(wp + 24576 + 32), a32 = pack8(wp + 24576 + 64);
    KEEP4(a00); KEEP4(a01); KEEP4(a02); KEEP4(a10); KEEP4(a11); KEEP4(a12);
    KEEP4(a20); KEEP4(a21); KEEP4(a22); KEEP4(a30); KEEP4(a31); KEEP4(a32);

    // ---- one-time: kk=3..6 into LDS: lw[j][m] = W[m][96+8j .. +8] ----
#pragma unroll
    for (int j = 0; j < 16; ++j)
        lw[j * N_ + n] = pack8(Wrec + (size_t)n * N_ + 96 + 8 * j);

    const float win0 = Win[n * IN_ + 0], win1 = Win[n * IN_ + 1], win2 = Win[n * IN_ + 2];
    const float win3 = Win[n * IN_ + 3], win4 = Win[n * IN_ + 4], win5 = Win[n * IN_ + 5];
    const float br = brec[n];
    const float NS = 0.6324555320336759f;  // sqrt(2/alpha * sigma^2)
    float h = 0.0f;

    float* ob = out + (size_t)b * T_ * N_;
    const float* rb = rnz + (size_t)b * T_ * N_;
    const float2* ubp = (const float2*)(u   + (size_t)b * T_ * IN_);
    const float2* nbp = (const float2*)(unz + (size_t)b * T_ * IN_);

    const uint4* wsb = nullptr;
    if constexpr (USE_WS) wsb = ws + (size_t)q * N_ + 64 * w + r16;
    const int lbase = q * N_ + 64 * w + r16;   // lw read base (kk=3, T=0)
    const uint4* hb0 = (const uint4*)&hbuf[0][0];
    const uint4* hb1 = (const uint4*)&hbuf[1][0];

    hbuf[0][n] = (_Float16)0.0f;

    // inp for t=0
    float2 cu0 = ubp[0], cu1 = ubp[1], cu2 = ubp[2];
    float2 cn0 = nbp[0], cn1 = nbp[1], cn2 = nbp[2];
    float inp_c = br;
    inp_c = fmaf(win0, fmaf(NS, cn0.x, cu0.x), inp_c);
    inp_c = fmaf(win1, fmaf(NS, cn0.y, cu0.y), inp_c);
    inp_c = fmaf(win2, fmaf(NS, cn1.x, cu1.x), inp_c);
    inp_c = fmaf(win3, fmaf(NS, cn1.y, cu1.y), inp_c);
    inp_c = fmaf(win4, fmaf(NS, cn2.x, cu2.x), inp_c);
    inp_c = fmaf(win5, fmaf(NS, cn2.y, cu2.y), inp_c);
    float rn_c = rb[n];
    __syncthreads();

#pragma unroll 1
    for (int t = 0; t < T_ - 1; ++t) {
        ob[(size_t)t * N_ + n] = h;   // states[t] (t=0: zeros)

        const uint4* hb = (t & 1) ? hb1 : hb0;         // B source (h_t, fp16)
        _Float16* hbw = (t & 1) ? &hbuf[0][0] : &hbuf[1][0];

        // B frag kk: hb[4*kk + q] = h[32kk + 8q .. +8]
        uint4 bf0 = hb[q], bf1 = hb[4 + q];

        // stream prologue: kk=7,8 in flight (2-deep window)
        uint4 sa0 = sld<USE_WS>(wsb, Wrec, rowA, q, 7, 0), sa1 = sld<USE_WS>(wsb, Wrec, rowA, q, 7, 1),
              sa2 = sld<USE_WS>(wsb, Wrec, rowA, q, 7, 2), sa3 = sld<USE_WS>(wsb, Wrec, rowA, q, 7, 3);
        uint4 sb0 = sld<USE_WS>(wsb, Wrec, rowA, q, 8, 0), sb1 = sld<USE_WS>(wsb, Wrec, rowA, q, 8, 1),
              sb2 = sld<USE_WS>(wsb, Wrec, rowA, q, 8, 2), sb3 = sld<USE_WS>(wsb, Wrec, rowA, q, 8, 3);

        // t+1 input prefetch (consumed at the h-update; issued after the
        // stream prologue so its HBM latency never gates stream vmcnt waits)
        const float rn_n = rb[(size_t)(t + 1) * N_ + n];
        const float2 pu0 = ubp[(t + 1) * 3 + 0], pu1 = ubp[(t + 1) * 3 + 1], pu2 = ubp[(t + 1) * 3 + 2];
        const float2 pn0 = nbp[(t + 1) * 3 + 0], pn1 = nbp[(t + 1) * 3 + 1], pn2 = nbp[(t + 1) * 3 + 2];

        const f32x4 zz = {0.0f, 0.0f, 0.0f, 0.0f};

        // ---- kk=0..2 from registers ----
        uint4 bf2 = hb[8 + q];
        f32x4 d0 = MFMA(a00, bf0, zz), d1 = MFMA(a10, bf0, zz),
              d2 = MFMA(a20, bf0, zz), d3 = MFMA(a30, bf0, zz);
        uint4 bf3 = hb[12 + q];
        d0 = MFMA(a01, bf1, d0); d1 = MFMA(a11, bf1, d1);
        d2 = MFMA(a21, bf1, d2); d3 = MFMA(a31, bf1, d3);
        uint4 bf4 = hb[16 + q];
        d0 = MFMA(a02, bf2, d0); d1 = MFMA(a12, bf2, d1);
        d2 = MFMA(a22, bf2, d2); d3 = MFMA(a32, bf2, d3);

        // ---- kk=3..6 from LDS ----
        uint4 l30 = lw[lbase + 0], l31 = lw[lbase + 16], l32 = lw[lbase + 32], l33 = lw[lbase + 48];
        uint4 bf5 = hb[20 + q];
        d0 = MFMA(l30, bf3, d0); d1 = MFMA(l31, bf3, d1);
        d2 = MFMA(l32, bf3, d2); d3 = MFMA(l33, bf3, d3);
        uint4 l40 = lw[lbase + 2048], l41 = lw[lbase + 2064], l42 = lw[lbase + 2080], l43 = lw[lbase + 2096];
        uint4 bf6 = hb[24 + q];
        d0 = MFMA(l40, bf4, d0); d1 = MFMA(l41, bf4, d1);
        d2 = MFMA(l42, bf4, d2); d3 = MFMA(l43, bf4, d3);
        uint4 l50 = lw[lbase + 4096], l51 = lw[lbase + 4112], l52 = lw[lbase + 4128], l53 = lw[lbase + 4144];
        uint4 bf7 = hb[28 + q];
        d0 = MFMA(l50, bf5, d0); d1 = MFMA(l51, bf5, d1);
        d2 = MFMA(l52, bf5, d2); d3 = MFMA(l53, bf5, d3);
        uint4 l60 = lw[lbase + 6144], l61 = lw[lbase + 6160], l62 = lw[lbase + 6176], l63 = lw[lbase + 6192];
        uint4 bf8 = hb[32 + q];
        d0 = MFMA(l60, bf6, d0); d1 = MFMA(l61, bf6, d1);
        d2 = MFMA(l62, bf6, d2); d3 = MFMA(l63, bf6, d3);

        // ---- kk=7..15 streamed, 2-deep rotating window ----
        uint4 bf9 = hb[36 + q];
        d0 = MFMA(sa0, bf7, d0); d1 = MFMA(sa1, bf7, d1);
        d2 = MFMA(sa2, bf7, d2); d3 = MFMA(sa3, bf7, d3);
        sa0 = sld<USE_WS>(wsb, Wrec, rowA, q, 9, 0); sa1 = sld<USE_WS>(wsb, Wrec, rowA, q, 9, 1);
        sa2 = sld<USE_WS>(wsb, Wrec, rowA, q, 9, 2); sa3 = sld<USE_WS>(wsb, Wrec, rowA, q, 9, 3);

        uint4 bf10 = hb[40 + q];
        d0 = MFMA(sb0, bf8, d0); d1 = MFMA(sb1, bf8, d1);
        d2 = MFMA(sb2, bf8, d2); d3 = MFMA(sb3, bf8, d3);
        sb0 = sld<USE_WS>(wsb, Wrec, rowA, q, 10, 0); sb1 = sld<USE_WS>(wsb, Wrec, rowA, q, 10, 1);
        sb2 = sld<USE_WS>(wsb, Wrec, rowA, q, 10, 2); sb3 = sld<USE_WS>(wsb, Wrec, rowA, q, 10, 3);

        uint4 bf11 = hb[44 + q];
        d0 = MFMA(sa0, bf9, d0); d1 = MFMA(sa1, bf9, d1);
        d2 = MFMA(sa2, bf9, d2); d3 = MFMA(sa3, bf9, d3);
        sa0 = sld<USE_WS>(wsb, Wrec, rowA, q, 11, 0); sa1 = sld<USE_WS>(wsb, Wrec, rowA, q, 11, 1);
        sa2 = sld<USE_WS>(wsb, Wrec, rowA, q, 11, 2); sa3 = sld<USE_WS>(wsb, Wrec, rowA, q, 11, 3);

        uint4 bf12 = hb[48 + q];
        d0 = MFMA(sb0, bf10, d0); d1 = MFMA(sb1, bf10, d1);
        d2 = MFMA(sb2, bf10, d2); d3 = MFMA(sb3, bf10, d3);
        sb0 = sld<USE_WS>(wsb, Wrec, rowA, q, 12, 0); sb1 = sld<USE_WS>(wsb, Wrec, rowA, q, 12, 1);
        sb2 = sld<USE_WS>(wsb, Wrec, rowA, q, 12, 2); sb3 = sld<USE_WS>(wsb, Wrec, rowA, q, 12, 3);

        uint4 bf13 = hb[52 + q];
        d0 = MFMA(sa0, bf11, d0); d1 = MFMA(sa1, bf11, d1);
        d2 = MFMA(sa2, bf11, d2); d3 = MFMA(sa3, bf11, d3);
        sa0 = sld<USE_WS>(wsb, Wrec, rowA, q, 13, 0); sa1 = sld<USE_WS>(wsb, Wrec, rowA, q, 13, 1);
        sa2 = sld<USE_WS>(wsb, Wrec, rowA, q, 13, 2); sa3 = sld<USE_WS>(wsb, Wrec, rowA, q, 13, 3);

        uint4 bf14 = hb[56 + q];
        d0 = MFMA(sb0, bf12, d0); d1 = MFMA(sb1, bf12, d1);
        d2 = MFMA(sb2, bf12, d2); d3 = MFMA(sb3, bf12, d3);
        sb0 = sld<USE_WS>(wsb, Wrec, rowA, q, 14, 0); sb1 = sld<USE_WS>(wsb, Wrec, rowA, q, 14, 1);
        sb2 = sld<USE_WS>(wsb, Wrec, rowA, q, 14, 2); sb3 = sld<USE_WS>(wsb, Wrec, rowA, q, 14, 3);

        uint4 bf15 = hb[60 + q];
        d0 = MFMA(sa0, bf13, d0); d1 = MFMA(sa1, bf13, d1);
        d2 = MFMA(sa2, bf13, d2); d3 = MFMA(sa3, bf13, d3);
        sa0 = sld<USE_WS>(wsb, Wrec, rowA, q, 15, 0); sa1 = sld<USE_WS>(wsb, Wrec, rowA, q, 15, 1);
        sa2 = sld<USE_WS>(wsb, Wrec, rowA, q, 15, 2); sa3 = sld<USE_WS>(wsb, Wrec, rowA, q, 15, 3);

        d0 = MFMA(sb0, bf14, d0); d1 = MFMA(sb1, bf14, d1);
        d2 = MFMA(sb2, bf14, d2); d3 = MFMA(sb3, bf14, d3);

        d0 = MFMA(sa0, bf15, d0); d1 = MFMA(sa1, bf15, d1);
        d2 = MFMA(sa2, bf15, d2); d3 = MFMA(sa3, bf15, d3);

        // ---- readout: lanes 0,16,32,48 own rows 4q..4q+3 of each tile ----
        if (r16 == 0) {
            *(f32x4*)(pre + 64 * w +  0 + 4 * q) = d0;
            *(f32x4*)(pre + 64 * w + 16 + 4 * q) = d1;
            *(f32x4*)(pre + 64 * w + 32 + 4 * q) = d2;
            *(f32x4*)(pre + 64 * w + 48 + 4 * q) = d3;
        }
        __syncthreads();

        const float prn = pre[n] + inp_c;
        h = 0.8f * h + 0.2f * (fmaxf(prn, 0.0f) + rn_c);
        hbw[n] = (_Float16)h;

        float inp_n = br;
        inp_n = fmaf(win0, fmaf(NS, pn0.x, pu0.x), inp_n);
        inp_n = fmaf(win1, fmaf(NS, pn0.y, pu0.y), inp_n);
        inp_n = fmaf(win2, fmaf(NS, pn1.x, pu1.x), inp_n);
        inp_n = fmaf(win3, fmaf(NS, pn1.y, pu1.y), inp_n);
        inp_n = fmaf(win4, fmaf(NS, pn2.x, pu2.x), inp_n);
        inp_n = fmaf(win5, fmaf(NS, pn2.y, pu2.y), inp_n);
        inp_c = inp_n;
        rn_c  = rn_n;
        __syncthreads();
    }
    ob[(size_t)(T_ - 1) * N_ + n] = h;  // states[511]
}

extern "C" void kernel_launch(void* const* d_in, const int* in_sizes, int n_in,
                              void* d_out, int out_size, void* d_ws, size_t ws_size,
                              hipStream_t stream) {
    const float* u    = (const float*)d_in[0];
    const float* unz  = (const float*)d_in[1];
    const float* rnz  = (const float*)d_in[2];
    const float* Wrec = (const float*)d_in[3];
    const float* brec = (const float*)d_in[4];
    const float* Win  = (const float*)d_in[5];
    float* out = (float*)d_out;

    const size_t ws_need = (size_t)36 * N_ * sizeof(uint4);  // 294912 B
    if (ws_size >= ws_need) {
        uint4* ws = (uint4*)d_ws;
        prep_tail_kernel<<<(36 * N_ + 255) / 256, 256, 0, stream>>>(Wrec, ws);
        rnn_scan_kernel<true><<<dim3(B_), dim3(512), 0, stream>>>(
            u, unz, rnz, Wrec, brec, Win, ws, out);
    } else {
        rnn_scan_kernel<false><<<dim3(B_), dim3(512), 0, stream>>>(
            u, unz, rnz, Wrec, brec, Win, nullptr, out);
    }
}